// Round 7
// baseline (393.544 us; speedup 1.0000x reference)
//
#include <hip/hip_runtime.h>
#include <math.h>

#define T_DIM 8192
#define D_DIM 7168
#define E_DIM 256
#define N_GROUPS 8
#define TOPK_GROUPS 4
#define TOP_K 8

#define N_TOK 256     // tokens per GEMM block: whole 256x256 tile, W read ONCE per 256 tokens
#define BK 32         // k per chunk (one 16x16x32 MFMA k-step)
#define CHUNK_HALVES (E_DIM * BK)   // 8192 halves = 16 KB image per chunk per hi/lo
#define WSCALE 512.0f
#define INV_WSCALE (1.0f / 512.0f)

typedef _Float16 half8 __attribute__((ext_vector_type(8)));
typedef _Float16 half4v __attribute__((ext_vector_type(4)));
typedef float floatx4 __attribute__((ext_vector_type(4)));

// global->LDS async DMA, 16B per lane. LDS dest is wave-uniform base
// (HW appends lane*16); global source is per-lane.
#define GLOAD_LDS16(gp, lp)                                                     \
    __builtin_amdgcn_global_load_lds(                                           \
        (const __attribute__((address_space(1))) void*)(gp),                    \
        (__attribute__((address_space(3))) void*)(lp), 16, 0, 0)

#define WAITV0 asm volatile("s_waitcnt vmcnt(0)" ::: "memory")
#define WAITLGKM asm volatile("s_waitcnt lgkmcnt(0)" ::: "memory")
#define SCHEDB __builtin_amdgcn_sched_barrier(0)

// ---------------------------------------------------------------------------
// Kernel 0: split W [D][E] fp32 -> wph/wpl as per-chunk LDS images (BK=32):
// chunk c holds k in [c*32,c*32+32); the half for (e, k=c*32+g*8+j) lives at
// halves-offset e*32 + ((g ^ ((e>>1)&3))<<3) + j. Linear DMA dest +
// pre-swizzled source (rule #21); swizzle keeps GEMM ds_read_b128 at <=2-way.
// ---------------------------------------------------------------------------
__global__ __launch_bounds__(256) void wprep_kernel(
    const float* __restrict__ w, _Float16* __restrict__ wph, _Float16* __restrict__ wpl)
{
    __shared__ float tile[64][65];
    const int k0 = blockIdx.x * 64, e0 = blockIdx.y * 64;
    const int tid = threadIdx.x;
    {
        const int kk = tid >> 4, e4 = (tid & 15) * 4;
#pragma unroll
        for (int i = 0; i < 4; i++) {
            const float4 v = *(const float4*)(w + (size_t)(k0 + kk + i * 16) * E_DIM + e0 + e4);
            tile[kk + i * 16][e4 + 0] = v.x;
            tile[kk + i * 16][e4 + 1] = v.y;
            tile[kk + i * 16][e4 + 2] = v.z;
            tile[kk + i * 16][e4 + 3] = v.w;
        }
    }
    __syncthreads();
    {
        const int ee = tid >> 4, kk4 = (tid & 15) * 4;
        const int c_in = (k0 + kk4) >> 5;       // global chunk index
        const int g = (kk4 >> 3) & 3;           // granule within chunk
        const int j0 = kk4 & 7;                 // 0 or 4
#pragma unroll
        for (int i = 0; i < 4; i++) {
            const int el = ee + i * 16;
            const int e = e0 + el;
            half4v hh, ll;
#pragma unroll
            for (int j = 0; j < 4; j++) {
                const float v = tile[kk4 + j][el] * WSCALE;
                const _Float16 h = (_Float16)v;
                hh[j] = h;
                ll[j] = (_Float16)(v - (float)h);
            }
            const size_t off = (size_t)c_in * CHUNK_HALVES + (size_t)e * BK +
                               (((g ^ ((e >> 1) & 3)) << 3) + j0);
            *(half4v*)(wph + off) = hh;
            *(half4v*)(wpl + off) = ll;
        }
    }
}

// ---------------------------------------------------------------------------
// Kernel 1: split-fp16 MFMA GEMM, 256x256 tile, 512 threads (8 waves =
// 4 expert-groups x 2 token-halves; each wave 64e x 128t, acc 4x8 frags).
// A: global_load_lds DMA from chunk image (shared by both token-halves).
// B: x tile staged to LDS (hi/lo split). One barrier per chunk; A/B double-
// buffered; per-chunk MFMA = 96/wave (~930 cyc/SIMD) covers load latency.
// KS=8 -> grid 8x32 = 256 blocks = 1/CU; gridDim.x=8=NXCD puts all blocks of
// one k-split on one XCD -> the 32KB/chunk W image is L2-resident per XCD.
// W traffic drops 940 -> 235 MB (the round-invariant ~10 TB/s cache-BW bound).
// ---------------------------------------------------------------------------
__device__ __forceinline__ void cvt_split8(const float4 v0, const float4 v1,
                                           half8& h, half8& l)
{
    float f[8] = {v0.x, v0.y, v0.z, v0.w, v1.x, v1.y, v1.z, v1.w};
#pragma unroll
    for (int j = 0; j < 8; j++) {
        const _Float16 hh = (_Float16)f[j];
        h[j] = hh;
        l[j] = (_Float16)(f[j] - (float)hh);
    }
}

// DMA chunk c's 16KB hi + 16KB lo images into As[buf] (4 DMAs/thread).
#define STAGE_A_DMA(c, buf)                                                   \
    do {                                                                      \
        const size_t cb_ = (size_t)(c) * CHUNK_HALVES;                        \
        const char* gh_ = (const char*)(wph + cb_) + wave * 1024 + lane * 16; \
        const char* gl_ = (const char*)(wpl + cb_) + wave * 1024 + lane * 16; \
        char* lh_ = (char*)&As[buf][0][0] + wave * 1024;                      \
        char* ll_ = (char*)&As[buf][1][0] + wave * 1024;                      \
        GLOAD_LDS16(gh_, lh_);                                                \
        GLOAD_LDS16(gh_ + 8192, lh_ + 8192);                                  \
        GLOAD_LDS16(gl_, ll_);                                                \
        GLOAD_LDS16(gl_ + 8192, ll_ + 8192);                                  \
    } while (0)

// write one (t,g) pair's hi/lo fragments into Bs[buf]
#define WRITE_B1(buf, t_, g_, h_, l_)                                         \
    do {                                                                      \
        const int boff_ = (t_) * BK + (((g_) ^ (((t_) >> 1) & 3)) << 3);      \
        *(half8*)&Bs[buf][0][boff_] = (h_);                                   \
        *(half8*)&Bs[buf][1][boff_] = (l_);                                   \
    } while (0)

#define COMPUTE_CHUNK(bb)                                                     \
    do {                                                                      \
        half8 ah[4], al[4];                                                   \
        _Pragma("unroll")                                                     \
        for (int mt_ = 0; mt_ < 4; mt_++) {                                   \
            const int e_ = we0 + mt_ * 16 + lm;                               \
            const int off_ = e_ * BK + ((kq ^ ((e_ >> 1) & 3)) << 3);         \
            ah[mt_] = *(const half8*)&As[bb][0][off_];                        \
            al[mt_] = *(const half8*)&As[bb][1][off_];                        \
        }                                                                     \
        __builtin_amdgcn_s_setprio(1);                                        \
        _Pragma("unroll")                                                     \
        for (int nt_ = 0; nt_ < 8; nt_++) {                                   \
            const int t_ = wt0 + nt_ * 16 + lm;                               \
            const int off_ = t_ * BK + ((kq ^ ((t_ >> 1) & 3)) << 3);         \
            const half8 bh = *(const half8*)&Bs[bb][0][off_];                 \
            const half8 bl = *(const half8*)&Bs[bb][1][off_];                 \
            _Pragma("unroll")                                                 \
            for (int mt_ = 0; mt_ < 4; mt_++) {                               \
                acc[mt_][nt_] = __builtin_amdgcn_mfma_f32_16x16x32_f16(ah[mt_], bh, acc[mt_][nt_], 0, 0, 0); \
                acc[mt_][nt_] = __builtin_amdgcn_mfma_f32_16x16x32_f16(ah[mt_], bl, acc[mt_][nt_], 0, 0, 0); \
                acc[mt_][nt_] = __builtin_amdgcn_mfma_f32_16x16x32_f16(al[mt_], bh, acc[mt_][nt_], 0, 0, 0); \
            }                                                                 \
        }                                                                     \
        __builtin_amdgcn_s_setprio(0);                                        \
    } while (0)

// stage x chunk at k-offset kk_ into Bs[buf] (loads -> cvt -> ds_write)
#define STAGE_B(kk_, buf)                                                     \
    do {                                                                      \
        const float4 a0_ = *(const float4*)(xrow0 + (kk_));                   \
        const float4 a1_ = *(const float4*)(xrow0 + (kk_) + 4);               \
        const float4 b0_ = *(const float4*)(xrow1 + (kk_));                   \
        const float4 b1_ = *(const float4*)(xrow1 + (kk_) + 4);               \
        half8 h_, l_;                                                         \
        cvt_split8(a0_, a1_, h_, l_);                                         \
        WRITE_B1(buf, bt0, bg0, h_, l_);                                      \
        cvt_split8(b0_, b1_, h_, l_);                                         \
        WRITE_B1(buf, bt0 + 128, bg0, h_, l_);                                \
    } while (0)

template <bool CONVW>
__global__ __launch_bounds__(512, 2) void gemm_split_kernel(
    const float* __restrict__ x, const _Float16* __restrict__ wph,
    const _Float16* __restrict__ wpl, const float* __restrict__ wraw,
    float* __restrict__ partial, int kslen)
{
    __shared__ _Float16 As[2][2][CHUNK_HALVES]; // [dbuf][hi/lo] = 64 KB
    __shared__ _Float16 Bs[2][2][N_TOK * BK];   // [dbuf][hi/lo] = 64 KB

    const int s = blockIdx.x, m = blockIdx.y;
    const int tid = threadIdx.x;
    const int k0 = s * kslen;
    const size_t t0 = (size_t)m * N_TOK;

    const int wave = tid >> 6, lane = tid & 63;
    const int lm = lane & 15, kq = lane >> 4; // fragment row / k-granule
    const int we0 = (wave & 3) * 64;          // wave's expert base
    const int wt0 = (wave >> 2) * 128;        // wave's token base

    // B staging map: thread handles (t,g) pairs tid and tid+512
    const int bt0 = tid >> 2;   // 0..127 (pair1 token = bt0+128)
    const int bg0 = tid & 3;    // k-granule
    const float* xrow0 = x + (t0 + bt0) * (size_t)D_DIM + bg0 * 8;
    const float* xrow1 = xrow0 + (size_t)128 * D_DIM;

    floatx4 acc[4][8];
#pragma unroll
    for (int mt = 0; mt < 4; mt++)
#pragma unroll
        for (int nt = 0; nt < 8; nt++) acc[mt][nt] = (floatx4)0.0f;

    const int nch = kslen / BK;   // 28 at KS=8 (even)
    const int cbase = k0 / BK;

    if (CONVW) {
        // synchronous fallback: build As image from raw w[k][e]
        for (int i = 0; i < nch; ++i) {
            const int kc = k0 + i * BK;
#pragma unroll
            for (int it = 0; it < 16; ++it) {
                const int f = tid + it * 512;       // 0..8191
                const int kk = f >> 8;              // 0..31
                const int e = f & 255;
                const float v = wraw[(size_t)(kc + kk) * E_DIM + e] * WSCALE;
                const _Float16 h = (_Float16)v;
                const int off = e * BK + ((((kk >> 3) ^ ((e >> 1) & 3))) << 3) + (kk & 7);
                As[0][0][off] = h;
                As[0][1][off] = (_Float16)(v - (float)h);
            }
            STAGE_B(kc, 0);
            __syncthreads();
            COMPUTE_CHUNK(0);
            __syncthreads();
        }
    } else {
        // ---- prologue: chunk 0 into buffer 0 ----
        STAGE_A_DMA(cbase, 0);
        STAGE_B(k0, 0);
        WAITV0; WAITLGKM; SCHEDB;
        __builtin_amdgcn_s_barrier();
        SCHEDB;

        // ---- main loop: DMA/stage chunk i+1 into nbuf, compute chunk i ----
        for (int i = 0; i < nch - 1; ++i) {
            const int buf = i & 1, nbuf = buf ^ 1;
            STAGE_A_DMA(cbase + i + 1, nbuf);
            COMPUTE_CHUNK(buf);
            STAGE_B(k0 + (i + 1) * BK, nbuf);
            WAITV0; WAITLGKM; SCHEDB;      // A DMAs landed; B writes done
            __builtin_amdgcn_s_barrier();
            SCHEDB;
        }
        // ---- last chunk ----
        COMPUTE_CHUNK((nch - 1) & 1);
    }

    // ---- epilogue: store raw z' partials. C/D: col(token)=lane&15, row(e)=(lane>>4)*4+r
    float* pout = partial + (size_t)s * T_DIM * E_DIM;
    const int rq = lane >> 4;
#pragma unroll
    for (int nt = 0; nt < 8; nt++) {
        const size_t t = t0 + wt0 + nt * 16 + lm;
#pragma unroll
        for (int mt = 0; mt < 4; mt++) {
            const int e = we0 + mt * 16 + rq * 4;
            *(floatx4*)(pout + t * E_DIM + e) = acc[mt][nt];
        }
    }
}

// ---------------------------------------------------------------------------
// Kernel 2: per-token routing. One wave per token, no barriers.
// Sums KS partials, z = sum * (1/512), score = sigmoid(z).
// ---------------------------------------------------------------------------
__global__ __launch_bounds__(64) void router_kernel(
    const float* __restrict__ partial, const float* __restrict__ bias,
    float* __restrict__ w_out, float* __restrict__ i_out, int ks)
{
    const int t = blockIdx.x;
    const int lane = threadIdx.x;

    __shared__ float sraw[E_DIM];

    float4 zv = make_float4(0.f, 0.f, 0.f, 0.f);
    for (int s = 0; s < ks; s++) {
        const float4 p = *(const float4*)(partial + (size_t)s * T_DIM * E_DIM +
                                          (size_t)t * E_DIM + lane * 4);
        zv.x += p.x; zv.y += p.y; zv.z += p.z; zv.w += p.w;
    }
    float4 sv;
    sv.x = 1.0f / (1.0f + expf(-zv.x * INV_WSCALE));
    sv.y = 1.0f / (1.0f + expf(-zv.y * INV_WSCALE));
    sv.z = 1.0f / (1.0f + expf(-zv.z * INV_WSCALE));
    sv.w = 1.0f / (1.0f + expf(-zv.w * INV_WSCALE));

    const float4 bz = *(const float4*)(bias + lane * 4);
    *(float4*)(&sraw[lane * 4]) = sv; // single wave: no barrier needed

    float sb[4];
    sb[0] = sv.x + bz.x; sb[1] = sv.y + bz.y; sb[2] = sv.z + bz.z; sb[3] = sv.w + bz.w;

    // group top-2 sum (8 lanes per group)
    float m1 = -INFINITY, m2 = -INFINITY;
#pragma unroll
    for (int j = 0; j < 4; j++) {
        const float v = sb[j];
        if (v > m1) { m2 = m1; m1 = v; }
        else if (v > m2) { m2 = v; }
    }
#pragma unroll
    for (int d = 1; d < 8; d <<= 1) {
        const float o1 = __shfl_xor(m1, d);
        const float o2 = __shfl_xor(m2, d);
        const float hi = fmaxf(m1, o1);
        const float lo = fminf(m1, o1);
        m2 = fmaxf(lo, fmaxf(m2, o2));
        m1 = hi;
    }
    const float gscore = m1 + m2;

    float gs[N_GROUPS];
#pragma unroll
    for (int g = 0; g < N_GROUPS; g++) gs[g] = __shfl(gscore, g * 8);

    unsigned gmask = 0u;
#pragma unroll
    for (int r = 0; r < TOPK_GROUPS; r++) {
        int best = 0; float bv = -INFINITY;
#pragma unroll
        for (int g = 0; g < N_GROUPS; g++) {
            const bool taken = (gmask >> g) & 1u;
            if (!taken && gs[g] > bv) { bv = gs[g]; best = g; }
        }
        gmask |= (1u << best);
    }

    const int myg = lane >> 3;
    const float keep = ((gmask >> myg) & 1u) ? 1.0f : 0.0f;
    float v[4];
#pragma unroll
    for (int j = 0; j < 4; j++) v[j] = keep * sb[j];

    int selIdx[TOP_K];
#pragma unroll
    for (int it = 0; it < TOP_K; it++) {
        float bv = -INFINITY; int bi = E_DIM;
#pragma unroll
        for (int j = 0; j < 4; j++) {
            if (v[j] > bv) { bv = v[j]; bi = 4 * lane + j; }
        }
#pragma unroll
        for (int off = 32; off > 0; off >>= 1) {
            const float ov = __shfl_down(bv, off);
            const int   oi = __shfl_down(bi, off);
            if (ov > bv || (ov == bv && oi < bi)) { bv = ov; bi = oi; }
        }
        bi = __shfl(bi, 0);
        selIdx[it] = bi;
        if (lane == (bi >> 2)) v[bi & 3] = -INFINITY;
    }

    float wv[TOP_K];
    float wsum = 0.0f;
#pragma unroll
    for (int it = 0; it < TOP_K; it++) {
        wv[it] = sraw[selIdx[it]];
        wsum += wv[it];
    }
    const float inv = 2.5f / (wsum + 1e-20f);

#pragma unroll
    for (int it = 0; it < TOP_K; it++) {
        if (lane == it) {
            w_out[(size_t)t * TOP_K + it] = wv[it] * inv;
            i_out[(size_t)t * TOP_K + it] = (float)selIdx[it];
        }
    }
}

// ---------------------------------------------------------------------------
extern "C" void kernel_launch(void* const* d_in, const int* in_sizes, int n_in,
                              void* d_out, int out_size, void* d_ws, size_t ws_size,
                              hipStream_t stream) {
    const float* x    = (const float*)d_in[0];
    const float* w    = (const float*)d_in[1];
    const float* bias = (const float*)d_in[2];

    float* w_out = (float*)d_out;
    float* i_out = w_out + (size_t)T_DIM * TOP_K;

    const size_t PART = (size_t)T_DIM * E_DIM * sizeof(float); // 8.39 MB
    const size_t WT   = (size_t)E_DIM * D_DIM * sizeof(_Float16); // 3.67 MB

    int KS; bool convw;
    if      (ws_size >= 8 * PART + 2 * WT) { KS = 8; convw = false; }
    else if (ws_size >= 4 * PART + 2 * WT) { KS = 4; convw = false; }
    else if (ws_size >= 2 * PART + 2 * WT) { KS = 2; convw = false; }
    else if (ws_size >= 1 * PART + 2 * WT) { KS = 1; convw = false; }
    else                                   { KS = 1; convw = true;  }

    float* partial = (float*)d_ws;
    _Float16* wph = (_Float16*)((char*)d_ws + (size_t)KS * PART);
    _Float16* wpl = wph + (size_t)E_DIM * D_DIM;

    const int kslen = D_DIM / KS;

    if (!convw) {
        wprep_kernel<<<dim3(D_DIM / 64, E_DIM / 64), 256, 0, stream>>>(w, wph, wpl);
        gemm_split_kernel<false><<<dim3(KS, T_DIM / N_TOK), 512, 0, stream>>>(
            x, wph, wpl, w, partial, kslen);
    } else {
        gemm_split_kernel<true><<<dim3(KS, T_DIM / N_TOK), 512, 0, stream>>>(
            x, wph, wpl, w, partial, kslen);
    }
    router_kernel<<<T_DIM, 64, 0, stream>>>(partial, bias, w_out, i_out, KS);
}